// Round 5
// baseline (1134.872 us; speedup 1.0000x reference)
//
#include <hip/hip_runtime.h>

// ConvLSTM fused, MI355X (gfx950). T=16, B=4, C=32, H=W=64, HID=64.
// Round 5: round-4 MFMA structure + memory-level parallelism fix:
//   - __launch_bounds__(64, 2): grid supplies only 2 waves/SIMD; let the
//     compiler use ~256 VGPR instead of starving ILP to hit 64 VGPR.
//   - per-tap BATCHED loads: all 36 A/B fragments loaded into register
//     arrays, then MFMAs consume them -> ~36 outstanding VMEM ops/wave
//     (round 4 was ~1-2 outstanding: load->wait->mfma serialization).
//   - c_state read hoisted to kernel start; `first` is a template param.
// Fallback to the verified fp32 kernel if ws_size is too small.

#define TSTEPS 16
#define BATCH  4
#define CX     32
#define HID    64
#define HW     64
#define PW     66

typedef short bf16x8 __attribute__((ext_vector_type(8)));
typedef float f32x4  __attribute__((ext_vector_type(4)));
typedef unsigned short u16x4 __attribute__((ext_vector_type(4)));

__device__ __forceinline__ float sigmoidf_(float x){ return 1.0f/(1.0f+__expf(-x)); }
__device__ __forceinline__ float tanhf_(float x){ return 1.0f - 2.0f/(__expf(2.0f*x)+1.0f); }

__device__ __forceinline__ unsigned short f2bf(float f){
  unsigned u = __float_as_uint(f);
  return (unsigned short)((u + 0x7FFFu + ((u>>16)&1u)) >> 16);
}
__device__ __forceinline__ float bf2f(unsigned short s){ return __uint_as_float(((unsigned)s)<<16); }

// ---------------- prep kernels (once per call) ----------------

__global__ __launch_bounds__(256) void prep_w(
    const float* __restrict__ wx, const float* __restrict__ wh,
    unsigned short* __restrict__ wxh, unsigned short* __restrict__ wxl,
    unsigned short* __restrict__ whh, unsigned short* __restrict__ whl)
{
  int idx = blockIdx.x*256 + threadIdx.x;
  if (idx < 9*256*HID){
    int tap = idx / (256*HID);
    int rem = idx - tap*(256*HID);
    int o = rem >> 6, c = rem & 63;
    float v = wh[(o*HID + c)*9 + tap];
    unsigned short h = f2bf(v);
    whh[idx] = h;
    whl[idx] = f2bf(v - bf2f(h));
  }
  if (idx < 9*256*CX){
    int tap = idx / (256*CX);
    int rem = idx - tap*(256*CX);
    int o = rem >> 5, c = rem & 31;
    float v = wx[(o*CX + c)*9 + tap];
    unsigned short h = f2bf(v);
    wxh[idx] = h;
    wxl[idx] = f2bf(v - bf2f(h));
  }
}

// x [T*B, CX, 64, 64] fp32 -> xT [T*B, 66, 66, 32] bf16 hi/lo (pads zero)
__global__ __launch_bounds__(256) void prep_x(
    const float* __restrict__ x,
    unsigned short* __restrict__ xh, unsigned short* __restrict__ xl)
{
  __shared__ float tile[CX][HW];
  const int tb = blockIdx.x, yp = blockIdx.y, tid = threadIdx.x;
  const int y = yp - 1;
  const bool rowok = (y >= 0 && y < HW);
  if (rowok){
    const float* src = x + (size_t)tb*CX*HW*HW + y*HW;
    for (int i = tid; i < CX*HW; i += 256){
      int c = i >> 6, xc = i & 63;
      tile[c][xc] = src[(size_t)c*HW*HW + xc];
    }
  }
  __syncthreads();
  size_t base = ((size_t)tb*PW + yp)*PW*CX;
  for (int i = tid; i < PW*CX; i += 256){
    int xp = i >> 5, c = i & 31;
    int xg = xp - 1;
    float v = (rowok && xg >= 0 && xg < HW) ? tile[c][xg] : 0.f;
    unsigned short h = f2bf(v);
    xh[base+i] = h;
    xl[base+i] = f2bf(v - bf2f(h));
  }
}

__global__ __launch_bounds__(256) void zero_ws(unsigned long long* p, size_t n64){
  size_t i = (size_t)blockIdx.x*256 + threadIdx.x;
  size_t stride = (size_t)gridDim.x*256;
  for (; i < n64; i += stride) p[i] = 0ull;
}

// ---------------- the MFMA step kernel ----------------
// grid: (8 = chunk*2 + xhalf, 64 = y, 4 = b), block = 64 (one wave)
// wave: M = 4 gates x 16 hid (chunk), N = 32 x-positions (xhalf)

#define MFMA(a,b,c) __builtin_amdgcn_mfma_f32_16x16x32_bf16((a),(b),(c),0,0,0)

template<int FIRST>
__global__ __launch_bounds__(64, 2) void step_mfma(
    const unsigned short* __restrict__ xTh, const unsigned short* __restrict__ xTl,
    const unsigned short* __restrict__ wxh, const unsigned short* __restrict__ wxl,
    const unsigned short* __restrict__ whh, const unsigned short* __restrict__ whl,
    const unsigned short* __restrict__ hph, const unsigned short* __restrict__ hpl,
    unsigned short* __restrict__ hch, unsigned short* __restrict__ hcl,
    const float* __restrict__ bxb, const float* __restrict__ bhb,
    float* __restrict__ c_state,   // [B][64y][64x][64hid] fp32
    float* __restrict__ h_out,     // [B][HID][64][64] fp32 (d_out slice t)
    int t)
{
  const int lane = threadIdx.x;
  const int nn = lane & 15, q = lane >> 4;
  const int chunk = blockIdx.x >> 1, xh_ = blockIdx.x & 1;
  const int y = blockIdx.y, b = blockIdx.z;
  const int m0 = chunk * 16;
  const int tb = t*BATCH + b;

  // hoisted epilogue loads (independent of tap loop)
  f32x4 cp[2];
  size_t coff[2];
#pragma unroll
  for (int ns = 0; ns < 2; ++ns){
    const int xg = xh_*32 + ns*16 + nn;
    coff[ns] = (((size_t)b*HW + y)*HW + xg)*HID + m0 + 4*q;
    cp[ns] = (f32x4){0.f, 0.f, 0.f, 0.f};
    if (!FIRST) cp[ns] = *(const f32x4*)&c_state[coff[ns]];
  }

  f32x4 acc[4][2];
#pragma unroll
  for (int g = 0; g < 4; ++g)
#pragma unroll
    for (int ns = 0; ns < 2; ++ns)
      acc[g][ns] = (f32x4){0.f, 0.f, 0.f, 0.f};

#pragma unroll 1
  for (int tap = 0; tap < 9; ++tap){
    const int ky = tap / 3;
    const int kx = tap - ky*3;
    const int yy = y + ky;            // padded row index

    // ======== phase 1: issue ALL loads for this tap (batched) ========
    bf16x8 bxh_[2], bxl_[2];
#pragma unroll
    for (int ns = 0; ns < 2; ++ns){
      const size_t boff = (((size_t)tb*PW + yy)*PW + (xh_*32 + ns*16 + kx + nn))*CX + q*8;
      bxh_[ns] = *(const bf16x8*)(xTh + boff);
      bxl_[ns] = *(const bf16x8*)(xTl + boff);
    }
    bf16x8 bhh_[2][2], bhl_[2][2];
    if (!FIRST){
#pragma unroll
      for (int kc = 0; kc < 2; ++kc)
#pragma unroll
        for (int ns = 0; ns < 2; ++ns){
          const size_t boff = (((size_t)b*PW + yy)*PW + (xh_*32 + ns*16 + kx + nn))*HID + kc*32 + q*8;
          bhh_[kc][ns] = *(const bf16x8*)(hph + boff);
          bhl_[kc][ns] = *(const bf16x8*)(hpl + boff);
        }
    }
    bf16x8 axh_[4], axl_[4];
    {
      const size_t aoff = ((size_t)(tap*256 + m0 + nn))*CX + q*8;
#pragma unroll
      for (int g = 0; g < 4; ++g){
        axh_[g] = *(const bf16x8*)(wxh + aoff + (size_t)g*HID*CX);
        axl_[g] = *(const bf16x8*)(wxl + aoff + (size_t)g*HID*CX);
      }
    }
    bf16x8 ahh_[2][4], ahl_[2][4];
    if (!FIRST){
#pragma unroll
      for (int kc = 0; kc < 2; ++kc){
        const size_t aoff = ((size_t)(tap*256 + m0 + nn))*HID + kc*32 + q*8;
#pragma unroll
        for (int g = 0; g < 4; ++g){
          ahh_[kc][g] = *(const bf16x8*)(whh + aoff + (size_t)g*HID*HID);
          ahl_[kc][g] = *(const bf16x8*)(whl + aoff + (size_t)g*HID*HID);
        }
      }
    }

    // ======== phase 2: MFMAs consume the batch ========
#pragma unroll
    for (int ns = 0; ns < 2; ++ns)
#pragma unroll
      for (int g = 0; g < 4; ++g){
        acc[g][ns] = MFMA(axh_[g], bxh_[ns], acc[g][ns]);
        acc[g][ns] = MFMA(axh_[g], bxl_[ns], acc[g][ns]);
        acc[g][ns] = MFMA(axl_[g], bxh_[ns], acc[g][ns]);
      }
    if (!FIRST){
#pragma unroll
      for (int kc = 0; kc < 2; ++kc)
#pragma unroll
        for (int ns = 0; ns < 2; ++ns)
#pragma unroll
          for (int g = 0; g < 4; ++g){
            acc[g][ns] = MFMA(ahh_[kc][g], bhh_[kc][ns], acc[g][ns]);
            acc[g][ns] = MFMA(ahh_[kc][g], bhl_[kc][ns], acc[g][ns]);
            acc[g][ns] = MFMA(ahl_[kc][g], bhh_[kc][ns], acc[g][ns]);
          }
    }
  }

  // ---- epilogue: LSTM update, register-local ----
  // D layout: col = lane&15 = n (x), row = q*4 + r (hid within chunk)
  f32x4 bxv[4], bhv[4];
#pragma unroll
  for (int g = 0; g < 4; ++g){
    bxv[g] = *(const f32x4*)&bxb[g*HID + m0 + 4*q];
    bhv[g] = *(const f32x4*)&bhb[g*HID + m0 + 4*q];
  }
#pragma unroll
  for (int ns = 0; ns < 2; ++ns){
    const int xg = xh_*32 + ns*16 + nn;
    f32x4 cn;
    float hn[4];
#pragma unroll
    for (int r = 0; r < 4; ++r){
      float iv = sigmoidf_(acc[0][ns][r] + bxv[0][r] + bhv[0][r]);
      float fv = sigmoidf_(acc[1][ns][r] + bxv[1][r] + bhv[1][r]);
      float gv = tanhf_  (acc[2][ns][r] + bxv[2][r] + bhv[2][r]);
      float ov = sigmoidf_(acc[3][ns][r] + bxv[3][r] + bhv[3][r]);
      float cnv = fv*cp[ns][r] + iv*gv;
      cn[r] = cnv;
      hn[r] = ov * tanhf_(cnv);
    }
    *(f32x4*)&c_state[coff[ns]] = cn;
#pragma unroll
    for (int r = 0; r < 4; ++r)
      h_out[(((size_t)b*HID + m0 + 4*q + r)*HW + y)*HW + xg] = hn[r];
    const size_t hoff = (((size_t)b*PW + (y+1))*PW + (xg+1))*HID + m0 + 4*q;
    u16x4 ph, pl;
#pragma unroll
    for (int r = 0; r < 4; ++r){
      unsigned short h = f2bf(hn[r]);
      ph[r] = h;
      pl[r] = f2bf(hn[r] - bf2f(h));
    }
    *(u16x4*)&hch[hoff] = ph;
    *(u16x4*)&hcl[hoff] = pl;
  }
}

// ---------------- fallback: fp32 kernel (verified round 3) ----------------

#define FCHUNK  8
#define FTILE_H 16
#define FROWS   (FTILE_H + 2)
#define FSTRIDE 68

__device__ __forceinline__ void do_chunk_f(
    float tile[FCHUNK][FROWS][FSTRIDE],
    const float* __restrict__ src,
    const float* __restrict__ wp0, const float* __restrict__ wp1,
    const float* __restrict__ wp2, const float* __restrict__ wp3,
    int gy0, int txg, int ty, int tid, float (&acc)[4][2][4])
{
  __syncthreads();
  for (int s = tid; s < FCHUNK * FROWS * 32; s += 128) {
    int c2 = s & 31;
    int rowid = s >> 5;
    int ic = rowid / FROWS;
    int r  = rowid - ic * FROWS;
    int gy = gy0 - 1 + r;
    if ((unsigned)gy < (unsigned)HW) {
      float2 v = *(const float2*)&src[(ic << 12) + (gy << 6) + (c2 << 1)];
      *(float2*)&tile[ic][r][2 + (c2 << 1)] = v;
    }
  }
  __syncthreads();
  for (int ic = 0; ic < FCHUNK; ++ic) {
    float w0[9], w1[9], w2[9], w3[9];
#pragma unroll
    for (int k = 0; k < 9; ++k) {
      w0[k] = wp0[ic*9+k]; w1[k] = wp1[ic*9+k];
      w2[k] = wp2[ic*9+k]; w3[k] = wp3[ic*9+k];
    }
    float rv[4][8];
#pragma unroll
    for (int rr = 0; rr < 4; ++rr) {
      const float* p = &tile[ic][2*ty+rr][4*txg];
      float4 a  = *(const float4*)p;
      float4 bb = *(const float4*)(p + 4);
      rv[rr][0]=a.x; rv[rr][1]=a.y; rv[rr][2]=a.z; rv[rr][3]=a.w;
      rv[rr][4]=bb.x; rv[rr][5]=bb.y; rv[rr][6]=bb.z; rv[rr][7]=bb.w;
    }
#pragma unroll
    for (int j = 0; j < 2; ++j)
#pragma unroll
      for (int dy = 0; dy < 3; ++dy)
#pragma unroll
        for (int qq = 0; qq < 4; ++qq)
#pragma unroll
          for (int dx = 0; dx < 3; ++dx) {
            float v = rv[j+dy][qq+dx+1];
            int k = dy*3+dx;
            acc[0][j][qq] = fmaf(v, w0[k], acc[0][j][qq]);
            acc[1][j][qq] = fmaf(v, w1[k], acc[1][j][qq]);
            acc[2][j][qq] = fmaf(v, w2[k], acc[2][j][qq]);
            acc[3][j][qq] = fmaf(v, w3[k], acc[3][j][qq]);
          }
  }
}

__global__ __launch_bounds__(128) void convlstm_step_f(
    const float* __restrict__ x_t, const float* __restrict__ h_prev,
    const float* __restrict__ w_x2h, const float* __restrict__ b_x2h,
    const float* __restrict__ w_h2h, const float* __restrict__ b_h2h,
    float* __restrict__ c_state, float* __restrict__ h_out, int first)
{
  __shared__ float tile[FCHUNK][FROWS][FSTRIDE];
  const int txg = threadIdx.x, ty = threadIdx.y;
  const int tid = ty*16 + txg;
  const int by = blockIdx.x, hc = blockIdx.y, b = blockIdx.z;
  const int gy0 = by * FTILE_H;
  {
    float2* p = (float2*)&tile[0][0][0];
    for (int i = tid; i < FCHUNK*FROWS*FSTRIDE/2; i += 128)
      p[i] = make_float2(0.f, 0.f);
  }
  float acc[4][2][4];
#pragma unroll
  for (int g = 0; g < 4; ++g)
#pragma unroll
    for (int j = 0; j < 2; ++j)
#pragma unroll
      for (int qq = 0; qq < 4; ++qq) acc[g][j][qq] = 0.f;
  {
    const float* wx0 = w_x2h + (size_t)(0*HID+hc)*CX*9;
    const float* wx1 = w_x2h + (size_t)(1*HID+hc)*CX*9;
    const float* wx2 = w_x2h + (size_t)(2*HID+hc)*CX*9;
    const float* wx3 = w_x2h + (size_t)(3*HID+hc)*CX*9;
    for (int c0 = 0; c0 < CX; c0 += FCHUNK)
      do_chunk_f(tile, x_t + ((size_t)(b*CX+c0) << 12),
                 wx0+c0*9, wx1+c0*9, wx2+c0*9, wx3+c0*9, gy0, txg, ty, tid, acc);
  }
  if (!first){
    const float* wh0 = w_h2h + (size_t)(0*HID+hc)*HID*9;
    const float* wh1 = w_h2h + (size_t)(1*HID+hc)*HID*9;
    const float* wh2 = w_h2h + (size_t)(2*HID+hc)*HID*9;
    const float* wh3 = w_h2h + (size_t)(3*HID+hc)*HID*9;
    for (int c0 = 0; c0 < HID; c0 += FCHUNK)
      do_chunk_f(tile, h_prev + ((size_t)(b*HID+c0) << 12),
                 wh0+c0*9, wh1+c0*9, wh2+c0*9, wh3+c0*9, gy0, txg, ty, tid, acc);
  }
  const float bi = b_x2h[0*HID+hc] + b_h2h[0*HID+hc];
  const float bf = b_x2h[1*HID+hc] + b_h2h[1*HID+hc];
  const float bg = b_x2h[2*HID+hc] + b_h2h[2*HID+hc];
  const float bo = b_x2h[3*HID+hc] + b_h2h[3*HID+hc];
#pragma unroll
  for (int j = 0; j < 2; ++j){
    const int row = gy0 + 2*ty + j;
    const int off = ((b*HID + hc)*HW + row)*HW + 4*txg;
    float4 cpv4 = make_float4(0.f,0.f,0.f,0.f);
    if (!first) cpv4 = *(const float4*)&c_state[off];
    float cn[4], hn[4];
    const float cpv[4] = {cpv4.x, cpv4.y, cpv4.z, cpv4.w};
#pragma unroll
    for (int qq = 0; qq < 4; ++qq){
      const float ig = sigmoidf_(acc[0][j][qq] + bi);
      const float fg = sigmoidf_(acc[1][j][qq] + bf);
      const float gg = tanhf_  (acc[2][j][qq] + bg);
      const float og = sigmoidf_(acc[3][j][qq] + bo);
      const float cnv = fg*cpv[qq] + ig*gg;
      cn[qq] = cnv;
      hn[qq] = og * tanhf_(cnv);
    }
    *(float4*)&c_state[off] = make_float4(cn[0],cn[1],cn[2],cn[3]);
    *(float4*)&h_out[off]   = make_float4(hn[0],hn[1],hn[2],hn[3]);
  }
}

// ---------------- launcher ----------------

extern "C" void kernel_launch(void* const* d_in, const int* in_sizes, int n_in,
                              void* d_out, int out_size, void* d_ws, size_t ws_size,
                              hipStream_t stream) {
  const float* x     = (const float*)d_in[0];
  const float* w_x2h = (const float*)d_in[1];
  const float* b_x2h = (const float*)d_in[2];
  const float* w_h2h = (const float*)d_in[3];
  const float* b_h2h = (const float*)d_in[4];
  float* out = (float*)d_out;

  // ws layout (256-aligned)
  size_t off = 0;
  auto alloc = [&](size_t bytes) -> char* {
    char* p = (char*)d_ws + off;
    off += (bytes + 255) & ~(size_t)255;
    return p;
  };
  float* c_state = (float*)alloc((size_t)BATCH*HW*HW*HID*4);          // 4 MB
  unsigned short* wxT_hi = (unsigned short*)alloc(9*256*CX*2);
  unsigned short* wxT_lo = (unsigned short*)alloc(9*256*CX*2);
  unsigned short* whT_hi = (unsigned short*)alloc(9*256*HID*2);
  unsigned short* whT_lo = (unsigned short*)alloc(9*256*HID*2);
  const size_t hT_bytes = (size_t)BATCH*PW*PW*HID*2;                  // 2,230,272
  unsigned short* hA_hi = (unsigned short*)alloc(hT_bytes);
  unsigned short* hA_lo = (unsigned short*)alloc(hT_bytes);
  unsigned short* hB_hi = (unsigned short*)alloc(hT_bytes);
  unsigned short* hB_lo = (unsigned short*)alloc(hT_bytes);
  const size_t xT_bytes = (size_t)TSTEPS*BATCH*PW*PW*CX*2;            // 17,842,176
  unsigned short* xT_hi = (unsigned short*)alloc(xT_bytes);
  unsigned short* xT_lo = (unsigned short*)alloc(xT_bytes);
  const size_t need = off;

  const size_t x_step = (size_t)BATCH*CX*HW*HW;
  const size_t h_step = (size_t)BATCH*HID*HW*HW;

  if (need <= ws_size) {
    // ---- MFMA path ----
    prep_w<<<(9*256*HID + 255)/256, 256, 0, stream>>>(
        w_x2h, w_h2h, wxT_hi, wxT_lo, whT_hi, whT_lo);
    prep_x<<<dim3(TSTEPS*BATCH, PW), 256, 0, stream>>>(x, xT_hi, xT_lo);
    zero_ws<<<1024, 256, 0, stream>>>((unsigned long long*)hA_hi, 4*hT_bytes/8);

    for (int t = 0; t < TSTEPS; ++t) {
      unsigned short* hp_hi = (t & 1) ? hA_hi : hB_hi;
      unsigned short* hp_lo = (t & 1) ? hA_lo : hB_lo;
      unsigned short* hc_hi = (t & 1) ? hB_hi : hA_hi;
      unsigned short* hc_lo = (t & 1) ? hB_lo : hA_lo;
      if (t == 0)
        step_mfma<1><<<dim3(8, HW, BATCH), 64, 0, stream>>>(
            xT_hi, xT_lo, wxT_hi, wxT_lo, whT_hi, whT_lo,
            hp_hi, hp_lo, hc_hi, hc_lo,
            b_x2h, b_h2h, c_state, out + (size_t)t*h_step, t);
      else
        step_mfma<0><<<dim3(8, HW, BATCH), 64, 0, stream>>>(
            xT_hi, xT_lo, wxT_hi, wxT_lo, whT_hi, whT_lo,
            hp_hi, hp_lo, hc_hi, hc_lo,
            b_x2h, b_h2h, c_state, out + (size_t)t*h_step, t);
    }
  } else {
    // ---- fallback fp32 path ----
    dim3 grid(HW / FTILE_H, HID, BATCH);
    dim3 block(16, 8);
    for (int t = 0; t < TSTEPS; ++t) {
      const float* x_t    = x + (size_t)t*x_step;
      const float* h_prev = (t == 0) ? x : out + (size_t)(t-1)*h_step;
      float* h_out        = out + (size_t)t*h_step;
      convlstm_step_f<<<grid, block, 0, stream>>>(
          x_t, h_prev, w_x2h, b_x2h, w_h2h, b_h2h, c_state, h_out, t == 0 ? 1 : 0);
    }
  }
}

// Round 6
// 1106.408 us; speedup vs baseline: 1.0257x; 1.0257x over previous
//
#include <hip/hip_runtime.h>

// ConvLSTM fused, MI355X (gfx950). T=16, B=4, C=32, H=W=64, HID=64.
// Round 6: force memory-level parallelism.
//   - sched_barrier(0) between load batch and MFMA batch per half-tap:
//     compiler may NOT sink loads to uses (R5 failure mode: VGPR=60 proved
//     loads were re-serialized, ~1-2 in flight, 450-cyc L2/L3 latency each).
//   - 4-wave blocks sharing (chunk, xh_), consecutive y: identical weight
//     load streams -> L1/MSHR merge (~4x less L2 A-traffic); adjacent-y
//     waves share 2/3 of B rows.
// Fallback to verified fp32 kernel if ws_size too small.

#define TSTEPS 16
#define BATCH  4
#define CX     32
#define HID    64
#define HW     64
#define PW     66

typedef short bf16x8 __attribute__((ext_vector_type(8)));
typedef float f32x4  __attribute__((ext_vector_type(4)));
typedef unsigned short u16x4 __attribute__((ext_vector_type(4)));

__device__ __forceinline__ float sigmoidf_(float x){ return 1.0f/(1.0f+__expf(-x)); }
__device__ __forceinline__ float tanhf_(float x){ return 1.0f - 2.0f/(__expf(2.0f*x)+1.0f); }

__device__ __forceinline__ unsigned short f2bf(float f){
  unsigned u = __float_as_uint(f);
  return (unsigned short)((u + 0x7FFFu + ((u>>16)&1u)) >> 16);
}
__device__ __forceinline__ float bf2f(unsigned short s){ return __uint_as_float(((unsigned)s)<<16); }

// ---------------- prep kernels (once per call) ----------------

__global__ __launch_bounds__(256) void prep_w(
    const float* __restrict__ wx, const float* __restrict__ wh,
    unsigned short* __restrict__ wxh, unsigned short* __restrict__ wxl,
    unsigned short* __restrict__ whh, unsigned short* __restrict__ whl)
{
  int idx = blockIdx.x*256 + threadIdx.x;
  if (idx < 9*256*HID){
    int tap = idx / (256*HID);
    int rem = idx - tap*(256*HID);
    int o = rem >> 6, c = rem & 63;
    float v = wh[(o*HID + c)*9 + tap];
    unsigned short h = f2bf(v);
    whh[idx] = h;
    whl[idx] = f2bf(v - bf2f(h));
  }
  if (idx < 9*256*CX){
    int tap = idx / (256*CX);
    int rem = idx - tap*(256*CX);
    int o = rem >> 5, c = rem & 31;
    float v = wx[(o*CX + c)*9 + tap];
    unsigned short h = f2bf(v);
    wxh[idx] = h;
    wxl[idx] = f2bf(v - bf2f(h));
  }
}

// x [T*B, CX, 64, 64] fp32 -> xT [T*B, 66, 66, 32] bf16 hi/lo (pads zero)
__global__ __launch_bounds__(256) void prep_x(
    const float* __restrict__ x,
    unsigned short* __restrict__ xh, unsigned short* __restrict__ xl)
{
  __shared__ float tile[CX][HW];
  const int tb = blockIdx.x, yp = blockIdx.y, tid = threadIdx.x;
  const int y = yp - 1;
  const bool rowok = (y >= 0 && y < HW);
  if (rowok){
    const float* src = x + (size_t)tb*CX*HW*HW + y*HW;
    for (int i = tid; i < CX*HW; i += 256){
      int c = i >> 6, xc = i & 63;
      tile[c][xc] = src[(size_t)c*HW*HW + xc];
    }
  }
  __syncthreads();
  size_t base = ((size_t)tb*PW + yp)*PW*CX;
  for (int i = tid; i < PW*CX; i += 256){
    int xp = i >> 5, c = i & 31;
    int xg = xp - 1;
    float v = (rowok && xg >= 0 && xg < HW) ? tile[c][xg] : 0.f;
    unsigned short h = f2bf(v);
    xh[base+i] = h;
    xl[base+i] = f2bf(v - bf2f(h));
  }
}

__global__ __launch_bounds__(256) void zero_ws(unsigned long long* p, size_t n64){
  size_t i = (size_t)blockIdx.x*256 + threadIdx.x;
  size_t stride = (size_t)gridDim.x*256;
  for (; i < n64; i += stride) p[i] = 0ull;
}

// ---------------- the MFMA step kernel ----------------
// grid: (8 = chunk*2 + xhalf, 16 = y/4, 4 = b), block = 256 (4 waves).
// wave w handles y = blockIdx.y*4 + w; all 4 waves share (chunk, xh_)
// -> identical weight-load streams (L1 merge).
// wave tile: M = 4 gates x 16 hid (chunk), N = 32 x-positions (xhalf).

#define MFMA(a,b,c) __builtin_amdgcn_mfma_f32_16x16x32_bf16((a),(b),(c),0,0,0)

template<int FIRST>
__global__ __launch_bounds__(256, 2) void step_mfma(
    const unsigned short* __restrict__ xTh, const unsigned short* __restrict__ xTl,
    const unsigned short* __restrict__ wxh, const unsigned short* __restrict__ wxl,
    const unsigned short* __restrict__ whh, const unsigned short* __restrict__ whl,
    const unsigned short* __restrict__ hph, const unsigned short* __restrict__ hpl,
    unsigned short* __restrict__ hch, unsigned short* __restrict__ hcl,
    const float* __restrict__ bxb, const float* __restrict__ bhb,
    float* __restrict__ c_state,   // [B][64y][64x][64hid] fp32
    float* __restrict__ h_out,     // [B][HID][64][64] fp32 (d_out slice t)
    int t)
{
  const int lane = threadIdx.x & 63;
  const int w    = threadIdx.x >> 6;       // wave id 0..3
  const int nn = lane & 15, q = lane >> 4;
  const int chunk = blockIdx.x >> 1, xh_ = blockIdx.x & 1;
  const int y = blockIdx.y * 4 + w;
  const int b = blockIdx.z;
  const int m0 = chunk * 16;
  const int tb = t*BATCH + b;

  f32x4 acc[4][2];
#pragma unroll
  for (int g = 0; g < 4; ++g)
#pragma unroll
    for (int ns = 0; ns < 2; ++ns)
      acc[g][ns] = (f32x4){0.f, 0.f, 0.f, 0.f};

#pragma unroll 1
  for (int tap = 0; tap < 9; ++tap){
    const int ky = tap / 3;
    const int kx = tap - ky*3;
    const int yy = y + ky;            // padded row index

    // ======== half-batch 1: x2h loads (12), then MFMAs (24) ========
    bf16x8 bxh_[2], bxl_[2], axh_[4], axl_[4];
#pragma unroll
    for (int ns = 0; ns < 2; ++ns){
      const size_t boff = (((size_t)tb*PW + yy)*PW + (xh_*32 + ns*16 + kx + nn))*CX + q*8;
      bxh_[ns] = *(const bf16x8*)(xTh + boff);
      bxl_[ns] = *(const bf16x8*)(xTl + boff);
    }
    {
      const size_t aoff = ((size_t)(tap*256 + m0 + nn))*CX + q*8;
#pragma unroll
      for (int g = 0; g < 4; ++g){
        axh_[g] = *(const bf16x8*)(wxh + aoff + (size_t)g*HID*CX);
        axl_[g] = *(const bf16x8*)(wxl + aoff + (size_t)g*HID*CX);
      }
    }
    __builtin_amdgcn_sched_barrier(0);   // loads stay above; MFMAs below
#pragma unroll
    for (int ns = 0; ns < 2; ++ns)
#pragma unroll
      for (int g = 0; g < 4; ++g){
        acc[g][ns] = MFMA(axh_[g], bxh_[ns], acc[g][ns]);
        acc[g][ns] = MFMA(axh_[g], bxl_[ns], acc[g][ns]);
        acc[g][ns] = MFMA(axl_[g], bxh_[ns], acc[g][ns]);
      }
    __builtin_amdgcn_sched_barrier(0);

    // ======== half-batch 2: h2h loads (24), then MFMAs (48) ========
    if (!FIRST){
      bf16x8 bhh_[2][2], bhl_[2][2], ahh_[2][4], ahl_[2][4];
#pragma unroll
      for (int kc = 0; kc < 2; ++kc)
#pragma unroll
        for (int ns = 0; ns < 2; ++ns){
          const size_t boff = (((size_t)b*PW + yy)*PW + (xh_*32 + ns*16 + kx + nn))*HID + kc*32 + q*8;
          bhh_[kc][ns] = *(const bf16x8*)(hph + boff);
          bhl_[kc][ns] = *(const bf16x8*)(hpl + boff);
        }
#pragma unroll
      for (int kc = 0; kc < 2; ++kc){
        const size_t aoff = ((size_t)(tap*256 + m0 + nn))*HID + kc*32 + q*8;
#pragma unroll
        for (int g = 0; g < 4; ++g){
          ahh_[kc][g] = *(const bf16x8*)(whh + aoff + (size_t)g*HID*HID);
          ahl_[kc][g] = *(const bf16x8*)(whl + aoff + (size_t)g*HID*HID);
        }
      }
      __builtin_amdgcn_sched_barrier(0);
#pragma unroll
      for (int kc = 0; kc < 2; ++kc)
#pragma unroll
        for (int ns = 0; ns < 2; ++ns)
#pragma unroll
          for (int g = 0; g < 4; ++g){
            acc[g][ns] = MFMA(ahh_[kc][g], bhh_[kc][ns], acc[g][ns]);
            acc[g][ns] = MFMA(ahh_[kc][g], bhl_[kc][ns], acc[g][ns]);
            acc[g][ns] = MFMA(ahl_[kc][g], bhh_[kc][ns], acc[g][ns]);
          }
      __builtin_amdgcn_sched_barrier(0);
    }
  }

  // ---- epilogue: LSTM update, register-local ----
  // D layout: col = lane&15 = n (x), row = q*4 + r (hid within chunk)
  f32x4 bxv[4], bhv[4];
#pragma unroll
  for (int g = 0; g < 4; ++g){
    bxv[g] = *(const f32x4*)&bxb[g*HID + m0 + 4*q];
    bhv[g] = *(const f32x4*)&bhb[g*HID + m0 + 4*q];
  }
#pragma unroll
  for (int ns = 0; ns < 2; ++ns){
    const int xg = xh_*32 + ns*16 + nn;
    const size_t coff = (((size_t)b*HW + y)*HW + xg)*HID + m0 + 4*q;
    f32x4 cp = (f32x4){0.f, 0.f, 0.f, 0.f};
    if (!FIRST) cp = *(const f32x4*)&c_state[coff];
    f32x4 cn;
    float hn[4];
#pragma unroll
    for (int r = 0; r < 4; ++r){
      float iv = sigmoidf_(acc[0][ns][r] + bxv[0][r] + bhv[0][r]);
      float fv = sigmoidf_(acc[1][ns][r] + bxv[1][r] + bhv[1][r]);
      float gv = tanhf_  (acc[2][ns][r] + bxv[2][r] + bhv[2][r]);
      float ov = sigmoidf_(acc[3][ns][r] + bxv[3][r] + bhv[3][r]);
      float cnv = fv*cp[r] + iv*gv;
      cn[r] = cnv;
      hn[r] = ov * tanhf_(cnv);
    }
    *(f32x4*)&c_state[coff] = cn;
#pragma unroll
    for (int r = 0; r < 4; ++r)
      h_out[(((size_t)b*HID + m0 + 4*q + r)*HW + y)*HW + xg] = hn[r];
    const size_t hoff = (((size_t)b*PW + (y+1))*PW + (xg+1))*HID + m0 + 4*q;
    u16x4 ph, pl;
#pragma unroll
    for (int r = 0; r < 4; ++r){
      unsigned short h = f2bf(hn[r]);
      ph[r] = h;
      pl[r] = f2bf(hn[r] - bf2f(h));
    }
    *(u16x4*)&hch[hoff] = ph;
    *(u16x4*)&hcl[hoff] = pl;
  }
}

// ---------------- fallback: fp32 kernel (verified round 3) ----------------

#define FCHUNK  8
#define FTILE_H 16
#define FROWS   (FTILE_H + 2)
#define FSTRIDE 68

__device__ __forceinline__ void do_chunk_f(
    float tile[FCHUNK][FROWS][FSTRIDE],
    const float* __restrict__ src,
    const float* __restrict__ wp0, const float* __restrict__ wp1,
    const float* __restrict__ wp2, const float* __restrict__ wp3,
    int gy0, int txg, int ty, int tid, float (&acc)[4][2][4])
{
  __syncthreads();
  for (int s = tid; s < FCHUNK * FROWS * 32; s += 128) {
    int c2 = s & 31;
    int rowid = s >> 5;
    int ic = rowid / FROWS;
    int r  = rowid - ic * FROWS;
    int gy = gy0 - 1 + r;
    if ((unsigned)gy < (unsigned)HW) {
      float2 v = *(const float2*)&src[(ic << 12) + (gy << 6) + (c2 << 1)];
      *(float2*)&tile[ic][r][2 + (c2 << 1)] = v;
    }
  }
  __syncthreads();
  for (int ic = 0; ic < FCHUNK; ++ic) {
    float w0[9], w1[9], w2[9], w3[9];
#pragma unroll
    for (int k = 0; k < 9; ++k) {
      w0[k] = wp0[ic*9+k]; w1[k] = wp1[ic*9+k];
      w2[k] = wp2[ic*9+k]; w3[k] = wp3[ic*9+k];
    }
    float rv[4][8];
#pragma unroll
    for (int rr = 0; rr < 4; ++rr) {
      const float* p = &tile[ic][2*ty+rr][4*txg];
      float4 a  = *(const float4*)p;
      float4 bb = *(const float4*)(p + 4);
      rv[rr][0]=a.x; rv[rr][1]=a.y; rv[rr][2]=a.z; rv[rr][3]=a.w;
      rv[rr][4]=bb.x; rv[rr][5]=bb.y; rv[rr][6]=bb.z; rv[rr][7]=bb.w;
    }
#pragma unroll
    for (int j = 0; j < 2; ++j)
#pragma unroll
      for (int dy = 0; dy < 3; ++dy)
#pragma unroll
        for (int qq = 0; qq < 4; ++qq)
#pragma unroll
          for (int dx = 0; dx < 3; ++dx) {
            float v = rv[j+dy][qq+dx+1];
            int k = dy*3+dx;
            acc[0][j][qq] = fmaf(v, w0[k], acc[0][j][qq]);
            acc[1][j][qq] = fmaf(v, w1[k], acc[1][j][qq]);
            acc[2][j][qq] = fmaf(v, w2[k], acc[2][j][qq]);
            acc[3][j][qq] = fmaf(v, w3[k], acc[3][j][qq]);
          }
  }
}

__global__ __launch_bounds__(128) void convlstm_step_f(
    const float* __restrict__ x_t, const float* __restrict__ h_prev,
    const float* __restrict__ w_x2h, const float* __restrict__ b_x2h,
    const float* __restrict__ w_h2h, const float* __restrict__ b_h2h,
    float* __restrict__ c_state, float* __restrict__ h_out, int first)
{
  __shared__ float tile[FCHUNK][FROWS][FSTRIDE];
  const int txg = threadIdx.x, ty = threadIdx.y;
  const int tid = ty*16 + txg;
  const int by = blockIdx.x, hc = blockIdx.y, b = blockIdx.z;
  const int gy0 = by * FTILE_H;
  {
    float2* p = (float2*)&tile[0][0][0];
    for (int i = tid; i < FCHUNK*FROWS*FSTRIDE/2; i += 128)
      p[i] = make_float2(0.f, 0.f);
  }
  float acc[4][2][4];
#pragma unroll
  for (int g = 0; g < 4; ++g)
#pragma unroll
    for (int j = 0; j < 2; ++j)
#pragma unroll
      for (int qq = 0; qq < 4; ++qq) acc[g][j][qq] = 0.f;
  {
    const float* wx0 = w_x2h + (size_t)(0*HID+hc)*CX*9;
    const float* wx1 = w_x2h + (size_t)(1*HID+hc)*CX*9;
    const float* wx2 = w_x2h + (size_t)(2*HID+hc)*CX*9;
    const float* wx3 = w_x2h + (size_t)(3*HID+hc)*CX*9;
    for (int c0 = 0; c0 < CX; c0 += FCHUNK)
      do_chunk_f(tile, x_t + ((size_t)(b*CX+c0) << 12),
                 wx0+c0*9, wx1+c0*9, wx2+c0*9, wx3+c0*9, gy0, txg, ty, tid, acc);
  }
  if (!first){
    const float* wh0 = w_h2h + (size_t)(0*HID+hc)*HID*9;
    const float* wh1 = w_h2h + (size_t)(1*HID+hc)*HID*9;
    const float* wh2 = w_h2h + (size_t)(2*HID+hc)*HID*9;
    const float* wh3 = w_h2h + (size_t)(3*HID+hc)*HID*9;
    for (int c0 = 0; c0 < HID; c0 += FCHUNK)
      do_chunk_f(tile, h_prev + ((size_t)(b*HID+c0) << 12),
                 wh0+c0*9, wh1+c0*9, wh2+c0*9, wh3+c0*9, gy0, txg, ty, tid, acc);
  }
  const float bi = b_x2h[0*HID+hc] + b_h2h[0*HID+hc];
  const float bf = b_x2h[1*HID+hc] + b_h2h[1*HID+hc];
  const float bg = b_x2h[2*HID+hc] + b_h2h[2*HID+hc];
  const float bo = b_x2h[3*HID+hc] + b_h2h[3*HID+hc];
#pragma unroll
  for (int j = 0; j < 2; ++j){
    const int row = gy0 + 2*ty + j;
    const int off = ((b*HID + hc)*HW + row)*HW + 4*txg;
    float4 cpv4 = make_float4(0.f,0.f,0.f,0.f);
    if (!first) cpv4 = *(const float4*)&c_state[off];
    float cn[4], hn[4];
    const float cpv[4] = {cpv4.x, cpv4.y, cpv4.z, cpv4.w};
#pragma unroll
    for (int qq = 0; qq < 4; ++qq){
      const float ig = sigmoidf_(acc[0][j][qq] + bi);
      const float fg = sigmoidf_(acc[1][j][qq] + bf);
      const float gg = tanhf_  (acc[2][j][qq] + bg);
      const float og = sigmoidf_(acc[3][j][qq] + bo);
      const float cnv = fg*cpv[qq] + ig*gg;
      cn[qq] = cnv;
      hn[qq] = og * tanhf_(cnv);
    }
    *(float4*)&c_state[off] = make_float4(cn[0],cn[1],cn[2],cn[3]);
    *(float4*)&h_out[off]   = make_float4(hn[0],hn[1],hn[2],hn[3]);
  }
}

// ---------------- launcher ----------------

extern "C" void kernel_launch(void* const* d_in, const int* in_sizes, int n_in,
                              void* d_out, int out_size, void* d_ws, size_t ws_size,
                              hipStream_t stream) {
  const float* x     = (const float*)d_in[0];
  const float* w_x2h = (const float*)d_in[1];
  const float* b_x2h = (const float*)d_in[2];
  const float* w_h2h = (const float*)d_in[3];
  const float* b_h2h = (const float*)d_in[4];
  float* out = (float*)d_out;

  // ws layout (256-aligned)
  size_t off = 0;
  auto alloc = [&](size_t bytes) -> char* {
    char* p = (char*)d_ws + off;
    off += (bytes + 255) & ~(size_t)255;
    return p;
  };
  float* c_state = (float*)alloc((size_t)BATCH*HW*HW*HID*4);          // 4 MB
  unsigned short* wxT_hi = (unsigned short*)alloc(9*256*CX*2);
  unsigned short* wxT_lo = (unsigned short*)alloc(9*256*CX*2);
  unsigned short* whT_hi = (unsigned short*)alloc(9*256*HID*2);
  unsigned short* whT_lo = (unsigned short*)alloc(9*256*HID*2);
  const size_t hT_bytes = (size_t)BATCH*PW*PW*HID*2;                  // 2,230,272
  unsigned short* hA_hi = (unsigned short*)alloc(hT_bytes);
  unsigned short* hA_lo = (unsigned short*)alloc(hT_bytes);
  unsigned short* hB_hi = (unsigned short*)alloc(hT_bytes);
  unsigned short* hB_lo = (unsigned short*)alloc(hT_bytes);
  const size_t xT_bytes = (size_t)TSTEPS*BATCH*PW*PW*CX*2;            // 17,842,176
  unsigned short* xT_hi = (unsigned short*)alloc(xT_bytes);
  unsigned short* xT_lo = (unsigned short*)alloc(xT_bytes);
  const size_t need = off;

  const size_t x_step = (size_t)BATCH*CX*HW*HW;
  const size_t h_step = (size_t)BATCH*HID*HW*HW;

  if (need <= ws_size) {
    // ---- MFMA path ----
    prep_w<<<(9*256*HID + 255)/256, 256, 0, stream>>>(
        w_x2h, w_h2h, wxT_hi, wxT_lo, whT_hi, whT_lo);
    prep_x<<<dim3(TSTEPS*BATCH, PW), 256, 0, stream>>>(x, xT_hi, xT_lo);
    zero_ws<<<1024, 256, 0, stream>>>((unsigned long long*)hA_hi, 4*hT_bytes/8);

    for (int t = 0; t < TSTEPS; ++t) {
      unsigned short* hp_hi = (t & 1) ? hA_hi : hB_hi;
      unsigned short* hp_lo = (t & 1) ? hA_lo : hB_lo;
      unsigned short* hc_hi = (t & 1) ? hB_hi : hA_hi;
      unsigned short* hc_lo = (t & 1) ? hB_lo : hA_lo;
      if (t == 0)
        step_mfma<1><<<dim3(8, 16, BATCH), 256, 0, stream>>>(
            xT_hi, xT_lo, wxT_hi, wxT_lo, whT_hi, whT_lo,
            hp_hi, hp_lo, hc_hi, hc_lo,
            b_x2h, b_h2h, c_state, out + (size_t)t*h_step, t);
      else
        step_mfma<0><<<dim3(8, 16, BATCH), 256, 0, stream>>>(
            xT_hi, xT_lo, wxT_hi, wxT_lo, whT_hi, whT_lo,
            hp_hi, hp_lo, hc_hi, hc_lo,
            b_x2h, b_h2h, c_state, out + (size_t)t*h_step, t);
    }
  } else {
    // ---- fallback fp32 path ----
    dim3 grid(HW / FTILE_H, HID, BATCH);
    dim3 block(16, 8);
    for (int t = 0; t < TSTEPS; ++t) {
      const float* x_t    = x + (size_t)t*x_step;
      const float* h_prev = (t == 0) ? x : out + (size_t)(t-1)*h_step;
      float* h_out        = out + (size_t)t*h_step;
      convlstm_step_f<<<grid, block, 0, stream>>>(
          x_t, h_prev, w_x2h, b_x2h, w_h2h, b_h2h, c_state, h_out, t == 0 ? 1 : 0);
    }
  }
}

// Round 7
// 762.414 us; speedup vs baseline: 1.4885x; 1.4512x over previous
//
#include <hip/hip_runtime.h>

// ConvLSTM fused, MI355X (gfx950). T=16, B=4, C=32, H=W=64, HID=64.
// Round 7: LDS-staged MFMA step kernel.
//   Evidence R5/R6: per-lane global loads feeding MFMAs are serialized by the
//   compiler (MLP~1, 450cyc each). Fix: cooperative global->LDS staging (the
//   one pattern with natural MLP), hot loop = ds_read_b128 + MFMA only.
//   - block = (chunk 16hid, x-half 32px, 4-y slab), 256 thr / 4 waves
//   - LDS: x rows 6x(hi/lo) 26.1KB, h rows 6x(hi/lo x kc-plane) 52.2KB,
//     weight tap-ring dbuf 24KB -> 103KB, 1 block/CU
//   - all LDS fragments contiguous 1KB (kc-split planes) -> conflict-free
//   - weight-lo dropped (bf16: ah*bh + ah*bl): MFMAs 648->432/wave,
//     est. +1.5e-3 error vs 1.69e-2 budget
// Fallback to verified fp32 kernel if ws_size too small.

#define TSTEPS 16
#define BATCH  4
#define CX     32
#define HID    64
#define HW     64
#define PW     66
#define XSEG   34            // staged pixels per row segment (32 + 2 halo)
#define SEGS   (XSEG * 32)   // shorts per plane-row = 1088

typedef short bf16x8 __attribute__((ext_vector_type(8)));
typedef float f32x4  __attribute__((ext_vector_type(4)));
typedef unsigned short u16x4 __attribute__((ext_vector_type(4)));

__device__ __forceinline__ float sigmoidf_(float x){ return 1.0f/(1.0f+__expf(-x)); }
__device__ __forceinline__ float tanhf_(float x){ return 1.0f - 2.0f/(__expf(2.0f*x)+1.0f); }

__device__ __forceinline__ unsigned short f2bf(float f){
  unsigned u = __float_as_uint(f);
  return (unsigned short)((u + 0x7FFFu + ((u>>16)&1u)) >> 16);
}
__device__ __forceinline__ float bf2f(unsigned short s){ return __uint_as_float(((unsigned)s)<<16); }

// ---------------- prep kernels (once per call) ----------------

// weights -> bf16 hi, block-contiguous tap slices:
// wxT[(tap*4+chunk)*2048 + g*512 + h16*32 + c]            (4 KB per (tap,chunk))
// whT[(tap*4+chunk)*4096 + kc*2048 + g*512 + h16*32 + c32] (8 KB per (tap,chunk))
__global__ __launch_bounds__(256) void prep_w(
    const float* __restrict__ wx, const float* __restrict__ wh,
    unsigned short* __restrict__ wxT, unsigned short* __restrict__ whT)
{
  int idx = blockIdx.x*256 + threadIdx.x;
  if (idx < 9*256*64){
    int tap = idx / (256*64);
    int rem = idx - tap*(256*64);
    int o = rem >> 6, c = rem & 63;
    int g = o >> 6, chunk = (o >> 4) & 3, h16 = o & 15;
    int kc = c >> 5, c32 = c & 31;
    whT[(size_t)(tap*4 + chunk)*4096 + kc*2048 + g*512 + h16*32 + c32] =
        f2bf(wh[(o*HID + c)*9 + tap]);
  }
  if (idx < 9*256*32){
    int tap = idx / (256*32);
    int rem = idx - tap*(256*32);
    int o = rem >> 5, c = rem & 31;
    int g = o >> 6, chunk = (o >> 4) & 3, h16 = o & 15;
    wxT[(size_t)(tap*4 + chunk)*2048 + g*512 + h16*32 + c] =
        f2bf(wx[(o*CX + c)*9 + tap]);
  }
}

// x [T*B, CX, 64, 64] fp32 -> xT [T*B, 66, 66, 32] bf16 hi/lo (pads zero)
__global__ __launch_bounds__(256) void prep_x(
    const float* __restrict__ x,
    unsigned short* __restrict__ xh, unsigned short* __restrict__ xl)
{
  __shared__ float tile[CX][HW];
  const int tb = blockIdx.x, yp = blockIdx.y, tid = threadIdx.x;
  const int y = yp - 1;
  const bool rowok = (y >= 0 && y < HW);
  if (rowok){
    const float* src = x + (size_t)tb*CX*HW*HW + y*HW;
    for (int i = tid; i < CX*HW; i += 256){
      int c = i >> 6, xc = i & 63;
      tile[c][xc] = src[(size_t)c*HW*HW + xc];
    }
  }
  __syncthreads();
  size_t base = ((size_t)tb*PW + yp)*PW*CX;
  for (int i = tid; i < PW*CX; i += 256){
    int xp = i >> 5, c = i & 31;
    int xg = xp - 1;
    float v = (rowok && xg >= 0 && xg < HW) ? tile[c][xg] : 0.f;
    unsigned short h = f2bf(v);
    xh[base+i] = h;
    xl[base+i] = f2bf(v - bf2f(h));
  }
}

__global__ __launch_bounds__(256) void zero_ws(unsigned long long* p, size_t n64){
  size_t i = (size_t)blockIdx.x*256 + threadIdx.x;
  size_t stride = (size_t)gridDim.x*256;
  for (; i < n64; i += stride) p[i] = 0ull;
}

// ---------------- the MFMA step kernel ----------------
// grid (8 = chunk*2+xh, 16 = yslab, 4 = b); block 256 thr = 4 waves.
// wave w handles y = yslab*4 + w; wave tile M=64 (4g x 16hid) x N=32 px.

#define MFMA(a,b,c) __builtin_amdgcn_mfma_f32_16x16x32_bf16((a),(b),(c),0,0,0)

template<int FIRST>
__global__ __launch_bounds__(256, 1) void step_mfma(
    const unsigned short* __restrict__ xTh, const unsigned short* __restrict__ xTl,
    const unsigned short* __restrict__ wxT, const unsigned short* __restrict__ whT,
    const unsigned short* __restrict__ hph, const unsigned short* __restrict__ hpl,
    unsigned short* __restrict__ hch, unsigned short* __restrict__ hcl,
    const float* __restrict__ bxb, const float* __restrict__ bhb,
    float* __restrict__ c_state,   // [B][64y][64x][64hid] fp32
    float* __restrict__ h_out,     // [B][HID][64][64] fp32 (d_out slice t)
    int t)
{
  __shared__ short xs[2][6*SEGS];      // [kind][row*SEGS + px*32 + c]  26.1 KB
  __shared__ short hs[2][2][6*SEGS];   // [kind][kc][...]               52.2 KB
  __shared__ short wxs[2][2048];       // tap dbuf                        8 KB
  __shared__ short whs[2][4096];       // tap dbuf                       16 KB

  const int tid  = threadIdx.x;
  const int lane = tid & 63;
  const int w    = tid >> 6;
  const int nn = lane & 15, q = lane >> 4;
  const int chunk = blockIdx.x >> 1, xh = blockIdx.x & 1;
  const int y0 = blockIdx.y * 4;
  const int b  = blockIdx.z;
  const int m0 = chunk * 16;
  const int y  = y0 + w;
  const int tb = t*BATCH + b;

  // ---- stage B rows (once per step) ----
  {
    const size_t xbase = ((size_t)tb*PW + y0)*PW + xh*32;   // pixel index
    for (int i = tid; i < 2*6*136; i += 256){
      int kind = i / (6*136);
      int rem  = i - kind*(6*136);
      int rr   = rem / 136;
      int c16  = rem - rr*136;
      const unsigned short* src = (kind ? xTl : xTh) + (xbase + (size_t)rr*PW)*CX + c16*8;
      *(uint4*)&xs[kind][rr*SEGS + c16*8] = *(const uint4*)src;
    }
    if (!FIRST){
      const size_t hbase = ((size_t)b*PW + y0)*PW + xh*32;
      for (int i = tid; i < 2*2*6*136; i += 256){
        int kind = i / (2*6*136);
        int rem  = i - kind*(2*6*136);
        int rr   = rem / (2*136);
        int rem2 = rem - rr*(2*136);
        int kc   = rem2 / 136;
        int c16  = rem2 - kc*136;
        int s    = c16 >> 2;            // pixel within segment
        int co   = (c16 & 3) * 8;       // channel offset (shorts)
        const unsigned short* src = (kind ? hpl : hph)
            + (hbase + (size_t)rr*PW + s)*HID + kc*32 + co;
        *(uint4*)&hs[kind][kc][rr*SEGS + c16*8] = *(const uint4*)src;
      }
    }
  }
  // ---- stage W tap 0 ----
  {
    const unsigned short* wsrc = wxT + (size_t)chunk*2048;
    const unsigned short* hsrc = whT + (size_t)chunk*4096;
    const int nW = FIRST ? 256 : 768;
    for (int i = tid; i < nW; i += 256){
      if (i < 256) *(uint4*)&wxs[0][i*8] = *(const uint4*)(wsrc + i*8);
      else         *(uint4*)&whs[0][(i-256)*8] = *(const uint4*)(hsrc + (size_t)(i-256)*8);
    }
  }
  __syncthreads();

  f32x4 acc[4][2];
#pragma unroll
  for (int g = 0; g < 4; ++g)
#pragma unroll
    for (int ns = 0; ns < 2; ++ns)
      acc[g][ns] = (f32x4){0.f, 0.f, 0.f, 0.f};

#pragma unroll 1
  for (int tap = 0; tap < 9; ++tap){
    const int buf = tap & 1, nbuf = buf ^ 1;
    // prefetch next tap's weights into the other buffer
    if (tap < 8){
      const unsigned short* wsrc = wxT + (size_t)((tap+1)*4 + chunk)*2048;
      const unsigned short* hsrc = whT + (size_t)((tap+1)*4 + chunk)*4096;
      const int nW = FIRST ? 256 : 768;
      for (int i = tid; i < nW; i += 256){
        if (i < 256) *(uint4*)&wxs[nbuf][i*8] = *(const uint4*)(wsrc + i*8);
        else         *(uint4*)&whs[nbuf][(i-256)*8] = *(const uint4*)(hsrc + (size_t)(i-256)*8);
      }
    }

    const int ky = tap / 3;
    const int kx = tap - ky*3;
    const int r0 = w + ky;            // staged row index 0..5
    const int ps = kx + nn;           // pixel base within segment

    // ---- x2h ----
    bf16x8 ax[4];
#pragma unroll
    for (int g = 0; g < 4; ++g)
      ax[g] = *(const bf16x8*)&wxs[buf][g*512 + nn*32 + q*8];
    bf16x8 bxf[2][2];   // [kind][ns]
#pragma unroll
    for (int ns = 0; ns < 2; ++ns){
      const int o = r0*SEGS + (ns*16 + ps)*32 + q*8;
      bxf[0][ns] = *(const bf16x8*)&xs[0][o];
      bxf[1][ns] = *(const bf16x8*)&xs[1][o];
    }
#pragma unroll
    for (int ns = 0; ns < 2; ++ns)
#pragma unroll
      for (int g = 0; g < 4; ++g){
        acc[g][ns] = MFMA(ax[g], bxf[0][ns], acc[g][ns]);
        acc[g][ns] = MFMA(ax[g], bxf[1][ns], acc[g][ns]);
      }

    // ---- h2h ----
    if (!FIRST){
      bf16x8 ah[2][4];
#pragma unroll
      for (int kc = 0; kc < 2; ++kc)
#pragma unroll
        for (int g = 0; g < 4; ++g)
          ah[kc][g] = *(const bf16x8*)&whs[buf][kc*2048 + g*512 + nn*32 + q*8];
      bf16x8 bhf[2][2][2];   // [kind][kc][ns]
#pragma unroll
      for (int kc = 0; kc < 2; ++kc)
#pragma unroll
        for (int ns = 0; ns < 2; ++ns){
          const int o = r0*SEGS + (ns*16 + ps)*32 + q*8;
          bhf[0][kc][ns] = *(const bf16x8*)&hs[0][kc][o];
          bhf[1][kc][ns] = *(const bf16x8*)&hs[1][kc][o];
        }
#pragma unroll
      for (int kc = 0; kc < 2; ++kc)
#pragma unroll
        for (int ns = 0; ns < 2; ++ns)
#pragma unroll
          for (int g = 0; g < 4; ++g){
            acc[g][ns] = MFMA(ah[kc][g], bhf[0][kc][ns], acc[g][ns]);
            acc[g][ns] = MFMA(ah[kc][g], bhf[1][kc][ns], acc[g][ns]);
          }
    }
    __syncthreads();
  }

  // ---- epilogue: LSTM update, register-local ----
  // D layout: col = lane&15 = n (x), row = q*4 + r (hid within chunk)
  f32x4 bxv[4], bhv[4];
#pragma unroll
  for (int g = 0; g < 4; ++g){
    bxv[g] = *(const f32x4*)&bxb[g*HID + m0 + 4*q];
    bhv[g] = *(const f32x4*)&bhb[g*HID + m0 + 4*q];
  }
#pragma unroll
  for (int ns = 0; ns < 2; ++ns){
    const int xg = xh*32 + ns*16 + nn;
    const size_t coff = (((size_t)b*HW + y)*HW + xg)*HID + m0 + 4*q;
    f32x4 cp = (f32x4){0.f, 0.f, 0.f, 0.f};
    if (!FIRST) cp = *(const f32x4*)&c_state[coff];
    f32x4 cn;
    float hn[4];
#pragma unroll
    for (int r = 0; r < 4; ++r){
      float iv = sigmoidf_(acc[0][ns][r] + bxv[0][r] + bhv[0][r]);
      float fv = sigmoidf_(acc[1][ns][r] + bxv[1][r] + bhv[1][r]);
      float gv = tanhf_  (acc[2][ns][r] + bxv[2][r] + bhv[2][r]);
      float ov = sigmoidf_(acc[3][ns][r] + bxv[3][r] + bhv[3][r]);
      float cnv = fv*cp[r] + iv*gv;
      cn[r] = cnv;
      hn[r] = ov * tanhf_(cnv);
    }
    *(f32x4*)&c_state[coff] = cn;
#pragma unroll
    for (int r = 0; r < 4; ++r)
      h_out[(((size_t)b*HID + m0 + 4*q + r)*HW + y)*HW + xg] = hn[r];
    const size_t hoff = (((size_t)b*PW + (y+1))*PW + (xg+1))*HID + m0 + 4*q;
    u16x4 ph, pl;
#pragma unroll
    for (int r = 0; r < 4; ++r){
      unsigned short h = f2bf(hn[r]);
      ph[r] = h;
      pl[r] = f2bf(hn[r] - bf2f(h));
    }
    *(u16x4*)&hch[hoff] = ph;
    *(u16x4*)&hcl[hoff] = pl;
  }
}

// ---------------- fallback: fp32 kernel (verified round 3) ----------------

#define FCHUNK  8
#define FTILE_H 16
#define FROWS   (FTILE_H + 2)
#define FSTRIDE 68

__device__ __forceinline__ void do_chunk_f(
    float tile[FCHUNK][FROWS][FSTRIDE],
    const float* __restrict__ src,
    const float* __restrict__ wp0, const float* __restrict__ wp1,
    const float* __restrict__ wp2, const float* __restrict__ wp3,
    int gy0, int txg, int ty, int tid, float (&acc)[4][2][4])
{
  __syncthreads();
  for (int s = tid; s < FCHUNK * FROWS * 32; s += 128) {
    int c2 = s & 31;
    int rowid = s >> 5;
    int ic = rowid / FROWS;
    int r  = rowid - ic * FROWS;
    int gy = gy0 - 1 + r;
    if ((unsigned)gy < (unsigned)HW) {
      float2 v = *(const float2*)&src[(ic << 12) + (gy << 6) + (c2 << 1)];
      *(float2*)&tile[ic][r][2 + (c2 << 1)] = v;
    }
  }
  __syncthreads();
  for (int ic = 0; ic < FCHUNK; ++ic) {
    float w0[9], w1[9], w2[9], w3[9];
#pragma unroll
    for (int k = 0; k < 9; ++k) {
      w0[k] = wp0[ic*9+k]; w1[k] = wp1[ic*9+k];
      w2[k] = wp2[ic*9+k]; w3[k] = wp3[ic*9+k];
    }
    float rv[4][8];
#pragma unroll
    for (int rr = 0; rr < 4; ++rr) {
      const float* p = &tile[ic][2*ty+rr][4*txg];
      float4 a  = *(const float4*)p;
      float4 bb = *(const float4*)(p + 4);
      rv[rr][0]=a.x; rv[rr][1]=a.y; rv[rr][2]=a.z; rv[rr][3]=a.w;
      rv[rr][4]=bb.x; rv[rr][5]=bb.y; rv[rr][6]=bb.z; rv[rr][7]=bb.w;
    }
#pragma unroll
    for (int j = 0; j < 2; ++j)
#pragma unroll
      for (int dy = 0; dy < 3; ++dy)
#pragma unroll
        for (int qq = 0; qq < 4; ++qq)
#pragma unroll
          for (int dx = 0; dx < 3; ++dx) {
            float v = rv[j+dy][qq+dx+1];
            int k = dy*3+dx;
            acc[0][j][qq] = fmaf(v, w0[k], acc[0][j][qq]);
            acc[1][j][qq] = fmaf(v, w1[k], acc[1][j][qq]);
            acc[2][j][qq] = fmaf(v, w2[k], acc[2][j][qq]);
            acc[3][j][qq] = fmaf(v, w3[k], acc[3][j][qq]);
          }
  }
}

__global__ __launch_bounds__(128) void convlstm_step_f(
    const float* __restrict__ x_t, const float* __restrict__ h_prev,
    const float* __restrict__ w_x2h, const float* __restrict__ b_x2h,
    const float* __restrict__ w_h2h, const float* __restrict__ b_h2h,
    float* __restrict__ c_state, float* __restrict__ h_out, int first)
{
  __shared__ float tile[FCHUNK][FROWS][FSTRIDE];
  const int txg = threadIdx.x, ty = threadIdx.y;
  const int tid = ty*16 + txg;
  const int by = blockIdx.x, hc = blockIdx.y, b = blockIdx.z;
  const int gy0 = by * FTILE_H;
  {
    float2* p = (float2*)&tile[0][0][0];
    for (int i = tid; i < FCHUNK*FROWS*FSTRIDE/2; i += 128)
      p[i] = make_float2(0.f, 0.f);
  }
  float acc[4][2][4];
#pragma unroll
  for (int g = 0; g < 4; ++g)
#pragma unroll
    for (int j = 0; j < 2; ++j)
#pragma unroll
      for (int qq = 0; qq < 4; ++qq) acc[g][j][qq] = 0.f;
  {
    const float* wx0 = w_x2h + (size_t)(0*HID+hc)*CX*9;
    const float* wx1 = w_x2h + (size_t)(1*HID+hc)*CX*9;
    const float* wx2 = w_x2h + (size_t)(2*HID+hc)*CX*9;
    const float* wx3 = w_x2h + (size_t)(3*HID+hc)*CX*9;
    for (int c0 = 0; c0 < CX; c0 += FCHUNK)
      do_chunk_f(tile, x_t + ((size_t)(b*CX+c0) << 12),
                 wx0+c0*9, wx1+c0*9, wx2+c0*9, wx3+c0*9, gy0, txg, ty, tid, acc);
  }
  if (!first){
    const float* wh0 = w_h2h + (size_t)(0*HID+hc)*HID*9;
    const float* wh1 = w_h2h + (size_t)(1*HID+hc)*HID*9;
    const float* wh2 = w_h2h + (size_t)(2*HID+hc)*HID*9;
    const float* wh3 = w_h2h + (size_t)(3*HID+hc)*HID*9;
    for (int c0 = 0; c0 < HID; c0 += FCHUNK)
      do_chunk_f(tile, h_prev + ((size_t)(b*HID+c0) << 12),
                 wh0+c0*9, wh1+c0*9, wh2+c0*9, wh3+c0*9, gy0, txg, ty, tid, acc);
  }
  const float bi = b_x2h[0*HID+hc] + b_h2h[0*HID+hc];
  const float bf = b_x2h[1*HID+hc] + b_h2h[1*HID+hc];
  const float bg = b_x2h[2*HID+hc] + b_h2h[2*HID+hc];
  const float bo = b_x2h[3*HID+hc] + b_h2h[3*HID+hc];
#pragma unroll
  for (int j = 0; j < 2; ++j){
    const int row = gy0 + 2*ty + j;
    const int off = ((b*HID + hc)*HW + row)*HW + 4*txg;
    float4 cpv4 = make_float4(0.f,0.f,0.f,0.f);
    if (!first) cpv4 = *(const float4*)&c_state[off];
    float cn[4], hn[4];
    const float cpv[4] = {cpv4.x, cpv4.y, cpv4.z, cpv4.w};
#pragma unroll
    for (int qq = 0; qq < 4; ++qq){
      const float ig = sigmoidf_(acc[0][j][qq] + bi);
      const float fg = sigmoidf_(acc[1][j][qq] + bf);
      const float gg = tanhf_  (acc[2][j][qq] + bg);
      const float og = sigmoidf_(acc[3][j][qq] + bo);
      const float cnv = fg*cpv[qq] + ig*gg;
      cn[qq] = cnv;
      hn[qq] = og * tanhf_(cnv);
    }
    *(float4*)&c_state[off] = make_float4(cn[0],cn[1],cn[2],cn[3]);
    *(float4*)&h_out[off]   = make_float4(hn[0],hn[1],hn[2],hn[3]);
  }
}

// ---------------- launcher ----------------

extern "C" void kernel_launch(void* const* d_in, const int* in_sizes, int n_in,
                              void* d_out, int out_size, void* d_ws, size_t ws_size,
                              hipStream_t stream) {
  const float* x     = (const float*)d_in[0];
  const float* w_x2h = (const float*)d_in[1];
  const float* b_x2h = (const float*)d_in[2];
  const float* w_h2h = (const float*)d_in[3];
  const float* b_h2h = (const float*)d_in[4];
  float* out = (float*)d_out;

  // ws layout (256-aligned)
  size_t off = 0;
  auto alloc = [&](size_t bytes) -> char* {
    char* p = (char*)d_ws + off;
    off += (bytes + 255) & ~(size_t)255;
    return p;
  };
  float* c_state = (float*)alloc((size_t)BATCH*HW*HW*HID*4);          // 4 MB
  unsigned short* wxT = (unsigned short*)alloc((size_t)9*4*2048*2);   // 147 KB
  unsigned short* whT = (unsigned short*)alloc((size_t)9*4*4096*2);   // 295 KB
  const size_t hT_bytes = (size_t)BATCH*PW*PW*HID*2;                  // 2,230,272
  unsigned short* hA_hi = (unsigned short*)alloc(hT_bytes);
  unsigned short* hA_lo = (unsigned short*)alloc(hT_bytes);
  unsigned short* hB_hi = (unsigned short*)alloc(hT_bytes);
  unsigned short* hB_lo = (unsigned short*)alloc(hT_bytes);
  const size_t xT_bytes = (size_t)TSTEPS*BATCH*PW*PW*CX*2;            // 17,842,176
  unsigned short* xT_hi = (unsigned short*)alloc(xT_bytes);
  unsigned short* xT_lo = (unsigned short*)alloc(xT_bytes);
  const size_t need = off;

  const size_t x_step = (size_t)BATCH*CX*HW*HW;
  const size_t h_step = (size_t)BATCH*HID*HW*HW;

  if (need <= ws_size) {
    // ---- MFMA path ----
    prep_w<<<(9*256*HID + 255)/256, 256, 0, stream>>>(w_x2h, w_h2h, wxT, whT);
    prep_x<<<dim3(TSTEPS*BATCH, PW), 256, 0, stream>>>(x, xT_hi, xT_lo);
    zero_ws<<<1024, 256, 0, stream>>>((unsigned long long*)hA_hi, 4*hT_bytes/8);

    for (int t = 0; t < TSTEPS; ++t) {
      unsigned short* hp_hi = (t & 1) ? hA_hi : hB_hi;
      unsigned short* hp_lo = (t & 1) ? hA_lo : hB_lo;
      unsigned short* hc_hi = (t & 1) ? hB_hi : hA_hi;
      unsigned short* hc_lo = (t & 1) ? hB_lo : hA_lo;
      if (t == 0)
        step_mfma<1><<<dim3(8, 16, BATCH), 256, 0, stream>>>(
            xT_hi, xT_lo, wxT, whT, hp_hi, hp_lo, hc_hi, hc_lo,
            b_x2h, b_h2h, c_state, out + (size_t)t*h_step, t);
      else
        step_mfma<0><<<dim3(8, 16, BATCH), 256, 0, stream>>>(
            xT_hi, xT_lo, wxT, whT, hp_hi, hp_lo, hc_hi, hc_lo,
            b_x2h, b_h2h, c_state, out + (size_t)t*h_step, t);
    }
  } else {
    // ---- fallback fp32 path ----
    dim3 grid(HW / FTILE_H, HID, BATCH);
    dim3 block(16, 8);
    for (int t = 0; t < TSTEPS; ++t) {
      const float* x_t    = x + (size_t)t*x_step;
      const float* h_prev = (t == 0) ? x : out + (size_t)(t-1)*h_step;
      float* h_out        = out + (size_t)t*h_step;
      convlstm_step_f<<<grid, block, 0, stream>>>(
          x_t, h_prev, w_x2h, b_x2h, w_h2h, b_h2h, c_state, h_out, t == 0 ? 1 : 0);
    }
  }
}

// Round 8
// 498.822 us; speedup vs baseline: 2.2751x; 1.5284x over previous
//
#include <hip/hip_runtime.h>

// ConvLSTM fused, MI355X (gfx950). T=16, B=4, C=32, H=W=64, HID=64.
// Round 8: R7 LDS-staged MFMA + (a) one 512-thr block per CU (8 waves,
// 8-row y-slab, single round -> latency overlap, staging amortized 2x),
// (b) conflict-free LDS layouts: x/h rows re-ordered to [q][px][8c] and
// weights to [g][q][h16][8c] so every fragment read is the canonical
// contiguous ds_read_b128 (R7 had 64B lane stride -> 1.77M bank conflicts).
// Fallback to verified fp32 kernel if ws_size too small.

#define TSTEPS 16
#define BATCH  4
#define CX     32
#define HID    64
#define HW     64
#define PW     66
#define QS     528     // shorts per q-slice row  = PW*8
#define XROW   2112    // shorts per x row  = 4*QS
#define HROW   4224    // shorts per h row  = 8*QS
#define LROW   1088    // shorts per staged LDS row segment = 4*34*8

typedef short bf16x8 __attribute__((ext_vector_type(8)));
typedef float f32x4  __attribute__((ext_vector_type(4)));
typedef unsigned short u16x4 __attribute__((ext_vector_type(4)));

__device__ __forceinline__ float sigmoidf_(float x){ return 1.0f/(1.0f+__expf(-x)); }
__device__ __forceinline__ float tanhf_(float x){ return 1.0f - 2.0f/(__expf(2.0f*x)+1.0f); }

__device__ __forceinline__ unsigned short f2bf(float f){
  unsigned u = __float_as_uint(f);
  return (unsigned short)((u + 0x7FFFu + ((u>>16)&1u)) >> 16);
}
__device__ __forceinline__ float bf2f(unsigned short s){ return __uint_as_float(((unsigned)s)<<16); }

// ---------------- prep kernels (once per call) ----------------

// weights, block-contiguous tap slices in lane-contiguous order:
// wxT[(tap*4+chunk)*2048 + (g*64 + q*16 + h16)*8 + c8]            (q=c>>3)
// whT[(tap*4+chunk)*4096 + kc*2048 + (g*64 + q*16 + h16)*8 + c8]  (kc=c>>5)
__global__ __launch_bounds__(256) void prep_w(
    const float* __restrict__ wx, const float* __restrict__ wh,
    unsigned short* __restrict__ wxT, unsigned short* __restrict__ whT)
{
  int idx = blockIdx.x*256 + threadIdx.x;
  if (idx < 9*256*64){
    int tap = idx / (256*64);
    int rem = idx - tap*(256*64);
    int o = rem >> 6, c = rem & 63;
    int g = o >> 6, chunk = (o >> 4) & 3, h16 = o & 15;
    int kc = c >> 5, cc = c & 31, q = cc >> 3, c8 = cc & 7;
    whT[(size_t)(tap*4 + chunk)*4096 + kc*2048 + (g*64 + q*16 + h16)*8 + c8] =
        f2bf(wh[(o*HID + c)*9 + tap]);
  }
  if (idx < 9*256*32){
    int tap = idx / (256*32);
    int rem = idx - tap*(256*32);
    int o = rem >> 5, c = rem & 31;
    int g = o >> 6, chunk = (o >> 4) & 3, h16 = o & 15;
    int q = c >> 3, c8 = c & 7;
    wxT[(size_t)(tap*4 + chunk)*2048 + (g*64 + q*16 + h16)*8 + c8] =
        f2bf(wx[(o*CX + c)*9 + tap]);
  }
}

// x [T*B, CX, 64, 64] fp32 -> xT [T*B][yp 66][q 4][xp 66][c8 8] bf16 hi/lo
__global__ __launch_bounds__(256) void prep_x(
    const float* __restrict__ x,
    unsigned short* __restrict__ xh, unsigned short* __restrict__ xl)
{
  __shared__ float tile[CX][HW];
  const int tb = blockIdx.x, yp = blockIdx.y, tid = threadIdx.x;
  const int y = yp - 1;
  const bool rowok = (y >= 0 && y < HW);
  if (rowok){
    const float* src = x + (size_t)tb*CX*HW*HW + y*HW;
    for (int i = tid; i < CX*HW; i += 256){
      int c = i >> 6, xc = i & 63;
      tile[c][xc] = src[(size_t)c*HW*HW + xc];
    }
  }
  __syncthreads();
  size_t base = ((size_t)tb*PW + yp)*XROW;
  for (int i = tid; i < PW*CX; i += 256){
    int xp = i >> 5, c = i & 31;
    int xg = xp - 1;
    float v = (rowok && xg >= 0 && xg < HW) ? tile[c][xg] : 0.f;
    unsigned short h = f2bf(v);
    size_t o = base + ((size_t)(c >> 3)*PW + xp)*8 + (c & 7);
    xh[o] = h;
    xl[o] = f2bf(v - bf2f(h));
  }
}

__global__ __launch_bounds__(256) void zero_ws(unsigned long long* p, size_t n64){
  size_t i = (size_t)blockIdx.x*256 + threadIdx.x;
  size_t stride = (size_t)gridDim.x*256;
  for (; i < n64; i += stride) p[i] = 0ull;
}

// ---------------- the MFMA step kernel ----------------
// grid (8 = chunk*2+xh, 8 = yslab, 4 = b) = 256 blocks; block 512 thr = 8 waves.
// wave w handles y = yslab*8 + w; wave tile M=64 (4g x 16hid) x N=32 px.
// h layout: [b][yp 66][kcq 8][xp 66][c8 8] bf16 hi/lo.

#define MFMA(a,b,c) __builtin_amdgcn_mfma_f32_16x16x32_bf16((a),(b),(c),0,0,0)

template<int FIRST>
__global__ __launch_bounds__(512, 2) void step_mfma(
    const unsigned short* __restrict__ xTh, const unsigned short* __restrict__ xTl,
    const unsigned short* __restrict__ wxT, const unsigned short* __restrict__ whT,
    const unsigned short* __restrict__ hph, const unsigned short* __restrict__ hpl,
    unsigned short* __restrict__ hch, unsigned short* __restrict__ hcl,
    const float* __restrict__ bxb, const float* __restrict__ bhb,
    float* __restrict__ c_state,   // [B][64y][64x][64hid] fp32
    float* __restrict__ h_out,     // [B][HID][64][64] fp32 (d_out slice t)
    int t)
{
  __shared__ short xs[2*10*LROW];     // [kind][row][q*34+px][8]   43.5 KB
  __shared__ short hs[2*2*10*LROW];   // [kind][kc][row][...]      87 KB
  __shared__ short wxs[2][2048];      // tap dbuf                   8 KB
  __shared__ short whs[2][4096];      // tap dbuf                  16 KB

  const int tid  = threadIdx.x;       // 0..511
  const int lane = tid & 63;
  const int w    = tid >> 6;          // wave 0..7
  const int nn = lane & 15, q = lane >> 4;
  const int chunk = blockIdx.x >> 1, xh = blockIdx.x & 1;
  const int y0 = blockIdx.y * 8;
  const int b  = blockIdx.z;
  const int m0 = chunk * 16;
  const int y  = y0 + w;
  const int tb = t*BATCH + b;

  // ---- stage B rows (once per step): coalesced loads, contiguous LDS ----
  {
    for (int i = tid; i < 2720; i += 512){       // x: 2 kinds x 10 rows x 4q x 34px
      int px = i % 34;
      int j  = i / 34;
      int qq = j & 3;
      int r2 = j >> 2;
      int r  = r2 % 10;
      int kind = r2 / 10;
      const unsigned short* src = (kind ? xTl : xTh)
          + ((size_t)tb*PW + y0 + r)*XROW + qq*QS + (xh*32 + px)*8;
      *(uint4*)&xs[(kind*10 + r)*LROW + (qq*34 + px)*8] = *(const uint4*)src;
    }
    if (!FIRST){
      for (int i = tid; i < 5440; i += 512){     // h: 2 kinds x 10 rows x 8kcq x 34px
        int px = i % 34;
        int j  = i / 34;
        int kcq = j & 7;
        int r2  = j >> 3;
        int r   = r2 % 10;
        int kind = r2 / 10;
        const unsigned short* src = (kind ? hpl : hph)
            + ((size_t)b*PW + y0 + r)*HROW + kcq*QS + (xh*32 + px)*8;
        int kc = kcq >> 2, qq = kcq & 3;
        *(uint4*)&hs[((kind*2 + kc)*10 + r)*LROW + (qq*34 + px)*8] = *(const uint4*)src;
      }
    }
  }
  // ---- stage W tap 0 ----
  {
    const unsigned short* wsrc = wxT + (size_t)chunk*2048;
    const unsigned short* hsrc = whT + (size_t)chunk*4096;
    const int nW = FIRST ? 256 : 768;
    for (int i = tid; i < nW; i += 512){
      if (i < 256) *(uint4*)&wxs[0][i*8] = *(const uint4*)(wsrc + i*8);
      else         *(uint4*)&whs[0][(i-256)*8] = *(const uint4*)(hsrc + (size_t)(i-256)*8);
    }
  }
  __syncthreads();

  f32x4 acc[4][2];
#pragma unroll
  for (int g = 0; g < 4; ++g)
#pragma unroll
    for (int ns = 0; ns < 2; ++ns)
      acc[g][ns] = (f32x4){0.f, 0.f, 0.f, 0.f};

#pragma unroll 1
  for (int tap = 0; tap < 9; ++tap){
    const int buf = tap & 1, nbuf = buf ^ 1;
    // prefetch next tap's weights into the other buffer
    if (tap < 8){
      const unsigned short* wsrc = wxT + (size_t)((tap+1)*4 + chunk)*2048;
      const unsigned short* hsrc = whT + (size_t)((tap+1)*4 + chunk)*4096;
      const int nW = FIRST ? 256 : 768;
      for (int i = tid; i < nW; i += 512){
        if (i < 256) *(uint4*)&wxs[nbuf][i*8] = *(const uint4*)(wsrc + i*8);
        else         *(uint4*)&whs[nbuf][(i-256)*8] = *(const uint4*)(hsrc + (size_t)(i-256)*8);
      }
    }

    const int ky = tap / 3;
    const int kx = tap - ky*3;
    const int r0 = w + ky;            // staged row index 0..9
    const int ps = kx + nn;           // pixel base within 34-px segment

    // ---- x2h ----  (all LDS reads lane-contiguous 16B)
    bf16x8 ax[4];
#pragma unroll
    for (int g = 0; g < 4; ++g)
      ax[g] = *(const bf16x8*)&wxs[buf][(g*64 + q*16 + nn)*8];
    bf16x8 bxf[2][2];   // [kind][ns]
#pragma unroll
    for (int ns = 0; ns < 2; ++ns){
      const int o = (q*34 + ns*16 + ps)*8;
      bxf[0][ns] = *(const bf16x8*)&xs[(0*10 + r0)*LROW + o];
      bxf[1][ns] = *(const bf16x8*)&xs[(1*10 + r0)*LROW + o];
    }
#pragma unroll
    for (int ns = 0; ns < 2; ++ns)
#pragma unroll
      for (int g = 0; g < 4; ++g){
        acc[g][ns] = MFMA(ax[g], bxf[0][ns], acc[g][ns]);
        acc[g][ns] = MFMA(ax[g], bxf[1][ns], acc[g][ns]);
      }

    // ---- h2h ----
    if (!FIRST){
      bf16x8 ah[2][4];
#pragma unroll
      for (int kc = 0; kc < 2; ++kc)
#pragma unroll
        for (int g = 0; g < 4; ++g)
          ah[kc][g] = *(const bf16x8*)&whs[buf][kc*2048 + (g*64 + q*16 + nn)*8];
      bf16x8 bhf[2][2][2];   // [kind][kc][ns]
#pragma unroll
      for (int kc = 0; kc < 2; ++kc)
#pragma unroll
        for (int ns = 0; ns < 2; ++ns){
          const int o = (q*34 + ns*16 + ps)*8;
          bhf[0][kc][ns] = *(const bf16x8*)&hs[((0*2 + kc)*10 + r0)*LROW + o];
          bhf[1][kc][ns] = *(const bf16x8*)&hs[((1*2 + kc)*10 + r0)*LROW + o];
        }
#pragma unroll
      for (int kc = 0; kc < 2; ++kc)
#pragma unroll
        for (int ns = 0; ns < 2; ++ns)
#pragma unroll
          for (int g = 0; g < 4; ++g){
            acc[g][ns] = MFMA(ah[kc][g], bhf[0][kc][ns], acc[g][ns]);
            acc[g][ns] = MFMA(ah[kc][g], bhf[1][kc][ns], acc[g][ns]);
          }
    }
    __syncthreads();
  }

  // ---- epilogue: LSTM update, register-local ----
  // D layout: col = lane&15 = n (x), row = q*4 + r (hid within chunk)
  f32x4 bxv[4], bhv[4];
#pragma unroll
  for (int g = 0; g < 4; ++g){
    bxv[g] = *(const f32x4*)&bxb[g*HID + m0 + 4*q];
    bhv[g] = *(const f32x4*)&bhb[g*HID + m0 + 4*q];
  }
  const int kc  = chunk >> 1;                       // h-layout indices for this
  const int qh  = ((chunk & 1) << 1) | (q >> 1);    // lane's 4 hid values
  const int c8b = (q & 1) * 4;
#pragma unroll
  for (int ns = 0; ns < 2; ++ns){
    const int xg = xh*32 + ns*16 + nn;
    const size_t coff = (((size_t)b*HW + y)*HW + xg)*HID + m0 + 4*q;
    f32x4 cp = (f32x4){0.f, 0.f, 0.f, 0.f};
    if (!FIRST) cp = *(const f32x4*)&c_state[coff];
    f32x4 cn;
    float hn[4];
#pragma unroll
    for (int r = 0; r < 4; ++r){
      float iv = sigmoidf_(acc[0][ns][r] + bxv[0][r] + bhv[0][r]);
      float fv = sigmoidf_(acc[1][ns][r] + bxv[1][r] + bhv[1][r]);
      float gv = tanhf_  (acc[2][ns][r] + bxv[2][r] + bhv[2][r]);
      float ov = sigmoidf_(acc[3][ns][r] + bxv[3][r] + bhv[3][r]);
      float cnv = fv*cp[r] + iv*gv;
      cn[r] = cnv;
      hn[r] = ov * tanhf_(cnv);
    }
    *(f32x4*)&c_state[coff] = cn;
#pragma unroll
    for (int r = 0; r < 4; ++r)
      h_out[(((size_t)b*HID + m0 + 4*q + r)*HW + y)*HW + xg] = hn[r];
    const size_t hoff = ((size_t)b*PW + (y+1))*HROW + (kc*4 + qh)*QS + (xg+1)*8 + c8b;
    u16x4 ph, pl;
#pragma unroll
    for (int r = 0; r < 4; ++r){
      unsigned short h = f2bf(hn[r]);
      ph[r] = h;
      pl[r] = f2bf(hn[r] - bf2f(h));
    }
    *(u16x4*)&hch[hoff] = ph;
    *(u16x4*)&hcl[hoff] = pl;
  }
}

// ---------------- fallback: fp32 kernel (verified round 3) ----------------

#define FCHUNK  8
#define FTILE_H 16
#define FROWS   (FTILE_H + 2)
#define FSTRIDE 68

__device__ __forceinline__ void do_chunk_f(
    float tile[FCHUNK][FROWS][FSTRIDE],
    const float* __restrict__ src,
    const float* __restrict__ wp0, const float* __restrict__ wp1,
    const float* __restrict__ wp2, const float* __restrict__ wp3,
    int gy0, int txg, int ty, int tid, float (&acc)[4][2][4])
{
  __syncthreads();
  for (int s = tid; s < FCHUNK * FROWS * 32; s += 128) {
    int c2 = s & 31;
    int rowid = s >> 5;
    int ic = rowid / FROWS;
    int r  = rowid - ic * FROWS;
    int gy = gy0 - 1 + r;
    if ((unsigned)gy < (unsigned)HW) {
      float2 v = *(const float2*)&src[(ic << 12) + (gy << 6) + (c2 << 1)];
      *(float2*)&tile[ic][r][2 + (c2 << 1)] = v;
    }
  }
  __syncthreads();
  for (int ic = 0; ic < FCHUNK; ++ic) {
    float w0[9], w1[9], w2[9], w3[9];
#pragma unroll
    for (int k = 0; k < 9; ++k) {
      w0[k] = wp0[ic*9+k]; w1[k] = wp1[ic*9+k];
      w2[k] = wp2[ic*9+k]; w3[k] = wp3[ic*9+k];
    }
    float rv[4][8];
#pragma unroll
    for (int rr = 0; rr < 4; ++rr) {
      const float* p = &tile[ic][2*ty+rr][4*txg];
      float4 a  = *(const float4*)p;
      float4 bb = *(const float4*)(p + 4);
      rv[rr][0]=a.x; rv[rr][1]=a.y; rv[rr][2]=a.z; rv[rr][3]=a.w;
      rv[rr][4]=bb.x; rv[rr][5]=bb.y; rv[rr][6]=bb.z; rv[rr][7]=bb.w;
    }
#pragma unroll
    for (int j = 0; j < 2; ++j)
#pragma unroll
      for (int dy = 0; dy < 3; ++dy)
#pragma unroll
        for (int qq = 0; qq < 4; ++qq)
#pragma unroll
          for (int dx = 0; dx < 3; ++dx) {
            float v = rv[j+dy][qq+dx+1];
            int k = dy*3+dx;
            acc[0][j][qq] = fmaf(v, w0[k], acc[0][j][qq]);
            acc[1][j][qq] = fmaf(v, w1[k], acc[1][j][qq]);
            acc[2][j][qq] = fmaf(v, w2[k], acc[2][j][qq]);
            acc[3][j][qq] = fmaf(v, w3[k], acc[3][j][qq]);
          }
  }
}

__global__ __launch_bounds__(128) void convlstm_step_f(
    const float* __restrict__ x_t, const float* __restrict__ h_prev,
    const float* __restrict__ w_x2h, const float* __restrict__ b_x2h,
    const float* __restrict__ w_h2h, const float* __restrict__ b_h2h,
    float* __restrict__ c_state, float* __restrict__ h_out, int first)
{
  __shared__ float tile[FCHUNK][FROWS][FSTRIDE];
  const int txg = threadIdx.x, ty = threadIdx.y;
  const int tid = ty*16 + txg;
  const int by = blockIdx.x, hc = blockIdx.y, b = blockIdx.z;
  const int gy0 = by * FTILE_H;
  {
    float2* p = (float2*)&tile[0][0][0];
    for (int i = tid; i < FCHUNK*FROWS*FSTRIDE/2; i += 128)
      p[i] = make_float2(0.f, 0.f);
  }
  float acc[4][2][4];
#pragma unroll
  for (int g = 0; g < 4; ++g)
#pragma unroll
    for (int j = 0; j < 2; ++j)
#pragma unroll
      for (int qq = 0; qq < 4; ++qq) acc[g][j][qq] = 0.f;
  {
    const float* wx0 = w_x2h + (size_t)(0*HID+hc)*CX*9;
    const float* wx1 = w_x2h + (size_t)(1*HID+hc)*CX*9;
    const float* wx2 = w_x2h + (size_t)(2*HID+hc)*CX*9;
    const float* wx3 = w_x2h + (size_t)(3*HID+hc)*CX*9;
    for (int c0 = 0; c0 < CX; c0 += FCHUNK)
      do_chunk_f(tile, x_t + ((size_t)(b*CX+c0) << 12),
                 wx0+c0*9, wx1+c0*9, wx2+c0*9, wx3+c0*9, gy0, txg, ty, tid, acc);
  }
  if (!first){
    const float* wh0 = w_h2h + (size_t)(0*HID+hc)*HID*9;
    const float* wh1 = w_h2h + (size_t)(1*HID+hc)*HID*9;
    const float* wh2 = w_h2h + (size_t)(2*HID+hc)*HID*9;
    const float* wh3 = w_h2h + (size_t)(3*HID+hc)*HID*9;
    for (int c0 = 0; c0 < HID; c0 += FCHUNK)
      do_chunk_f(tile, h_prev + ((size_t)(b*HID+c0) << 12),
                 wh0+c0*9, wh1+c0*9, wh2+c0*9, wh3+c0*9, gy0, txg, ty, tid, acc);
  }
  const float bi = b_x2h[0*HID+hc] + b_h2h[0*HID+hc];
  const float bf = b_x2h[1*HID+hc] + b_h2h[1*HID+hc];
  const float bg = b_x2h[2*HID+hc] + b_h2h[2*HID+hc];
  const float bo = b_x2h[3*HID+hc] + b_h2h[3*HID+hc];
#pragma unroll
  for (int j = 0; j < 2; ++j){
    const int row = gy0 + 2*ty + j;
    const int off = ((b*HID + hc)*HW + row)*HW + 4*txg;
    float4 cpv4 = make_float4(0.f,0.f,0.f,0.f);
    if (!first) cpv4 = *(const float4*)&c_state[off];
    float cn[4], hn[4];
    const float cpv[4] = {cpv4.x, cpv4.y, cpv4.z, cpv4.w};
#pragma unroll
    for (int qq = 0; qq < 4; ++qq){
      const float ig = sigmoidf_(acc[0][j][qq] + bi);
      const float fg = sigmoidf_(acc[1][j][qq] + bf);
      const float gg = tanhf_  (acc[2][j][qq] + bg);
      const float og = sigmoidf_(acc[3][j][qq] + bo);
      const float cnv = fg*cpv[qq] + ig*gg;
      cn[qq] = cnv;
      hn[qq] = og * tanhf_(cnv);
    }
    *(float4*)&c_state[off] = make_float4(cn[0],cn[1],cn[2],cn[3]);
    *(float4*)&h_out[off]   = make_float4(hn[0],hn[1],hn[2],hn[3]);
  }
}

// ---------------- launcher ----------------

extern "C" void kernel_launch(void* const* d_in, const int* in_sizes, int n_in,
                              void* d_out, int out_size, void* d_ws, size_t ws_size,
                              hipStream_t stream) {
  const float* x     = (const float*)d_in[0];
  const float* w_x2h = (const float*)d_in[1];
  const float* b_x2h = (const float*)d_in[2];
  const float* w_h2h = (const float*)d_in[3];
  const float* b_h2h = (const float*)d_in[4];
  float* out = (float*)d_out;

  // ws layout (256-aligned)
  size_t off = 0;
  auto alloc = [&](size_t bytes) -> char* {
    char* p = (char*)d_ws + off;
    off += (bytes + 255) & ~(size_t)255;
    return p;
  };
  float* c_state = (float*)alloc((size_t)BATCH*HW*HW*HID*4);          // 4 MB
  unsigned short* wxT = (unsigned short*)alloc((size_t)9*4*2048*2);   // 147 KB
  unsigned short* whT = (unsigned short*)alloc((size_t)9*4*4096*2);   // 295 KB
  const size_t hT_bytes = (size_t)BATCH*PW*HROW*2;                    // 2,230,272
  unsigned short* hA_hi = (unsigned short*)alloc(hT_bytes);
  unsigned short* hA_lo = (unsigned short*)alloc(hT_bytes);
  unsigned short* hB_hi = (unsigned short*)alloc(hT_bytes);
  unsigned short* hB_lo = (unsigned short*)alloc(hT_bytes);
  const size_t xT_bytes = (size_t)TSTEPS*BATCH*PW*XROW*2;             // 17,842,176
  unsigned short* xT_hi = (unsigned short*)alloc(xT_bytes);
  unsigned short* xT_lo = (unsigned short*)alloc(xT_bytes);
  const size_t need = off;

  const size_t x_step = (size_t)BATCH*CX*HW*HW;
  const size_t h_step = (size_t)BATCH*HID*HW*HW;

  if (need <= ws_size) {
    // ---- MFMA path ----
    prep_w<<<(9*256*HID + 255)/256, 256, 0, stream>>>(w_x2h, w_h2h, wxT, whT);
    prep_x<<<dim3(TSTEPS*BATCH, PW), 256, 0, stream>>>(x, xT_hi, xT_lo);
    zero_ws<<<1024, 256, 0, stream>>>((unsigned long long*)hA_hi, 4*hT_bytes/8);

    for (int t = 0; t < TSTEPS; ++t) {
      unsigned short* hp_hi = (t & 1) ? hA_hi : hB_hi;
      unsigned short* hp_lo = (t & 1) ? hA_lo : hB_lo;
      unsigned short* hc_hi = (t & 1) ? hB_hi : hA_hi;
      unsigned short* hc_lo = (t & 1) ? hB_lo : hA_lo;
      if (t == 0)
        step_mfma<1><<<dim3(8, 8, BATCH), 512, 0, stream>>>(
            xT_hi, xT_lo, wxT, whT, hp_hi, hp_lo, hc_hi, hc_lo,
            b_x2h, b_h2h, c_state, out + (size_t)t*h_step, t);
      else
        step_mfma<0><<<dim3(8, 8, BATCH), 512, 0, stream>>>(
            xT_hi, xT_lo, wxT, whT, hp_hi, hp_lo, hc_hi, hc_lo,
            b_x2h, b_h2h, c_state, out + (size_t)t*h_step, t);
    }
  } else {
    // ---- fallback fp32 path ----
    dim3 grid(HW / FTILE_H, HID, BATCH);
    dim3 block(16, 8);
    for (int t = 0; t < TSTEPS; ++t) {
      const float* x_t    = x + (size_t)t*x_step;
      const float* h_prev = (t == 0) ? x : out + (size_t)(t-1)*h_step;
      float* h_out        = out + (size_t)t*h_step;
      convlstm_step_f<<<grid, block, 0, stream>>>(
          x_t, h_prev, w_x2h, b_x2h, w_h2h, b_h2h, c_state, h_out, t == 0 ? 1 : 0);
    }
  }
}